// Round 2
// baseline (356.267 us; speedup 1.0000x reference)
//
#include <hip/hip_runtime.h>
#include <hip/hip_fp16.h>
#include <math.h>

#define TAU 0.5f   // |pivot|^2 threshold (f32) for the fast pivot path

// ---------------------------------------------------------------------------
// Fused kernel: 2306 blocks x 256 threads (structure = round 12).
//   bid % 9 == 8 (bid<2304)  -> conv block  cid = bid/9        (256 blocks)
//   else                     -> logdet block, key = lid        (2050 blocks)
//
// Round-17 delta: true residency increase. r15/r16 post-mortem: 76-VGPR
// (r12) and 56-VGPR+24.5KB-LDS (r16) BOTH land at 24 waves/CU (VGPR cap
// 6 w/SIMD vs LDS cap 6 blocks) -- occupancy was never actually raised.
// Now: REGC=46 reg cols + LDSC=18 LDS cols -> logdet LDS = 18432 B fits
// INSIDE the conv footprint (18944 B). With VGPR<=64 (launch_bounds 256,8):
// 8 blocks/CU x 4 waves = 32 waves/CU (+33% vs all prior rounds).
// Also moves 6 cols from the 5-instr LDS path to the 3-instr reg path.
// Inner reg loop = r12 verbatim (readlane broadcast, op_sel-folded swap):
// r8/r13/r14 established DS-pipe broadcasts and SALU swaps both regress.
// ---------------------------------------------------------------------------
#define REGC 46   // columns held in registers (sliding window)
#define LDSC 18   // columns staged in LDS (cols 46..63 at k=0)
#define PADC 49   // a2 size: chunk loop reads up to ceil(REGC/8)*8 = 48

__device__ __forceinline__ int h2i(__half2 h) { int i; __builtin_memcpy(&i, &h, 4); return i; }
__device__ __forceinline__ __half2 i2h(int i) { __half2 h; __builtin_memcpy(&h, &i, 4); return h; }

__global__ __launch_bounds__(256, 8) void fused_kernel(
    const float* __restrict__ x, const float* __restrict__ K,
    const float* __restrict__ bias, float* __restrict__ out,
    float* __restrict__ logdet) {
  // conv view:   w[576] + tile[64*65] = 4736 floats = 18944 B
  // logdet view: 4 waves x 18 cols x 64 rows of half2-as-int = 4608 ints
  __shared__ float smem[4736];               // 18944 B -> 8 blocks/CU
  int bid = blockIdx.x;
  int t = threadIdx.x;

  bool isConv = false;
  int cid = 0, lid = 0;
  if (bid < 2304) {
    int q9 = bid / 9, m9 = bid - q9 * 9;
    if (m9 == 8) { isConv = true; cid = q9; }
    else lid = bid - (bid + 1) / 9;          // 0..2047
  } else {
    lid = bid - 256;                         // 2048, 2049
  }

  if (isConv) {
    // ================= conv =================
    int b = cid >> 6, co = cid & 63;
    float* w = smem;                         // 576
    float* tile = smem + 576;                // 64*65

    for (int i = t; i < 576; i += 256) {
      float vv = K[(size_t)((b * 64 + co) * 64) * 9 + i];
      if (i == co * 9 + 4) vv += 1.0f;       // identity: ci==co, center tap
      w[i] = vv;
    }

    int ty = t >> 2;
    int tx = t & 3;
    int x0 = tx << 4;
    float bval = bias[b * 64 + co];
    float acc[16];
#pragma unroll
    for (int i = 0; i < 16; ++i) acc[i] = bval;

    const float* xb = x + (size_t)(b * 64) * 4096;
    for (int ci = 0; ci < 64; ++ci) {
      __syncthreads();                       // WAR on tile (and w on first iter)
      const float* xc = xb + (size_t)ci * 4096;
#pragma unroll
      for (int j = 0; j < 16; ++j) {
        int i = t + 256 * j;
        tile[(i >> 6) * 65 + (i & 63)] = xc[i];
      }
      __syncthreads();

      int ym = ((ty - 1) & 63) * 65;
      int yc = ty * 65;
      int yp = ((ty + 1) & 63) * 65;

      // one 18-wide row buffer per kernel-row: peak ~50 VGPR (fits 64 cap)
      {
        float wa = w[ci * 9 + 0], wb = w[ci * 9 + 1], wcc = w[ci * 9 + 2];
        float in[18];
#pragma unroll
        for (int ix = 0; ix < 18; ++ix) in[ix] = tile[ym + ((x0 + ix - 1) & 63)];
#pragma unroll
        for (int px = 0; px < 16; ++px)
          acc[px] = fmaf(wa, in[px], fmaf(wb, in[px + 1], fmaf(wcc, in[px + 2], acc[px])));
      }
      {
        float wa = w[ci * 9 + 3], wb = w[ci * 9 + 4], wcc = w[ci * 9 + 5];
        float in[18];
#pragma unroll
        for (int ix = 0; ix < 18; ++ix) in[ix] = tile[yc + ((x0 + ix - 1) & 63)];
#pragma unroll
        for (int px = 0; px < 16; ++px)
          acc[px] = fmaf(wa, in[px], fmaf(wb, in[px + 1], fmaf(wcc, in[px + 2], acc[px])));
      }
      {
        float wa = w[ci * 9 + 6], wb = w[ci * 9 + 7], wcc = w[ci * 9 + 8];
        float in[18];
#pragma unroll
        for (int ix = 0; ix < 18; ++ix) in[ix] = tile[yp + ((x0 + ix - 1) & 63)];
#pragma unroll
        for (int px = 0; px < 16; ++px)
          acc[px] = fmaf(wa, in[px], fmaf(wb, in[px + 1], fmaf(wcc, in[px + 2], acc[px])));
      }
    }

    float* op = out + (size_t)(b * 64 + co) * 4096 + ty * 64 + x0;
#pragma unroll
    for (int i = 0; i < 16; i += 4) {
      *(float4*)(op + i) = make_float4(acc[i], acc[i + 1], acc[i + 2], acc[i + 3]);
    }
    return;
  }

  // ================= logdet =================
  int* sm32 = (int*)smem;                    // [4 waves][18 cols][64 rows]
  int u, v;
  if (lid < 33) { u = 0; v = lid; }
  else if (lid < 2017) { int q = lid - 33; u = 1 + (q >> 6); v = q & 63; }
  else { u = 32; v = lid - 2017; }
  float weight = (((u & 31) == 0) && ((v & 31) == 0)) ? 1.0f : 2.0f;

  int b = t >> 6;                            // wave id == batch
  int r = t & 63;                            // lane == matrix row

  // twiddles w[kh*3+kw] = e^{-2*pi*i*(u*kh+v*kw)/64}; block-uniform -> SGPRs
  int swr[9], swi[9];
  {
    float Ar[3], Ai[3], Br[3], Bi[3];
    const float k2pi = -6.283185307179586f / 64.0f;
    float su, cu, sv, cv;
    __sincosf(k2pi * (float)u, &su, &cu);
    __sincosf(k2pi * (float)v, &sv, &cv);
    Ar[0] = 1.0f; Ai[0] = 0.0f; Ar[1] = cu; Ai[1] = su;
    Ar[2] = cu * cu - su * su; Ai[2] = 2.0f * cu * su;
    Br[0] = 1.0f; Bi[0] = 0.0f; Br[1] = cv; Bi[1] = sv;
    Br[2] = cv * cv - sv * sv; Bi[2] = 2.0f * cv * sv;
#pragma unroll
    for (int kh = 0; kh < 3; ++kh)
#pragma unroll
      for (int kw = 0; kw < 3; ++kw) {
        float wrv = Ar[kh] * Br[kw] - Ai[kh] * Bi[kw];
        float wiv = Ar[kh] * Bi[kw] + Ai[kh] * Br[kw];
        swr[kh * 3 + kw] = __builtin_amdgcn_readfirstlane(__float_as_int(wrv));
        swi[kh * 3 + kw] = __builtin_amdgcn_readfirstlane(__float_as_int(wiv));
      }
  }

  // Build row r of Khat: cols 0..REGC-1 -> registers, REGC..63 -> LDS.
  // Scalar loads keep build-phase VGPR peak under the 64 cap (K rows are
  // L1/L2 resident; r16 showed the extra VMEM issues are absorbed).
  __half2 a2[PADC];
  const float* Kp = K + (size_t)(b * 64 + r) * 576;
#pragma unroll
  for (int c = 0; c < 64; ++c) {
    float re = 0.0f, im = 0.0f;
#pragma unroll
    for (int t9 = 0; t9 < 9; ++t9) {
      float kv = Kp[c * 9 + t9];
      re = fmaf(kv, __int_as_float(swr[t9]), re);
      im = fmaf(kv, __int_as_float(swi[t9]), im);
    }
    if (c == r) { re += __int_as_float(swr[4]); im += __int_as_float(swi[4]); }
    __half2 h = __floats2half2_rn(re, im);
    if (c < REGC) a2[c] = h;
    else sm32[(b * LDSC + (c - REGC)) * 64 + r] = h2i(h);
  }
#pragma unroll
  for (int c = REGC; c < PADC; ++c)
    a2[c] = __floats2half2_rn(0.0f, 0.0f);   // pad slots for chunk overshoot

  bool active = true;
  float pivmag = 1.0f;                       // each lane's own pivot |.|^2 (f32)

  for (int k = 0; k < 63; ++k) {
    float fr0 = __low2float(a2[0]);
    float fi0 = __high2float(a2[0]);
    float mag = fmaf(fr0, fr0, fi0 * fi0);
    bool cand = active && (mag >= TAU);
    unsigned long long candm = __ballot(cand);
    int p;
    if (candm != 0ULL) {
      p = __ffsll(candm) - 1;                // fast path: first big-enough pivot
    } else {                                 // rare: all remaining pivots tiny
      float mm = active ? mag : -1.0f;
#pragma unroll
      for (int off = 32; off > 0; off >>= 1) mm = fmaxf(mm, __shfl_xor(mm, off));
      unsigned long long mx = __ballot(active && (mag == mm));
      if (mx == 0ULL) mx = __ballot(active); // degenerate (NaN) guard
      p = __ffsll(mx) - 1;
    }
    p &= 63;                                 // uniform (ballot-derived), valid lane

    bool isPiv = (r == p);
    pivmag = isPiv ? mag : pivmag;           // latch; log deferred to the end
    active = active && !isPiv;

    __half2 pivh = i2h(__builtin_amdgcn_readlane(h2i(a2[0]), p));
    float pr = __low2float(pivh);
    float pi = __high2float(pivh);
    float inv = __builtin_amdgcn_rcpf(fmaf(pr, pr, pi * pi));
    float fre = (fr0 * pr + fi0 * pi) * inv;
    float fim = (fi0 * pr - fr0 * pi) * inv;
    fre = active ? fre : 0.0f;               // pivot + retired lanes: shift-only
    fim = active ? fim : 0.0f;
    __half2 nfre2 = __float2half2_rn(-fre);                     // (-fre, -fre)
    __half2 fim2 = __halves2half2(__float2half_rn(fim),
                                  __float2half_rn(-fim));       // (fim, -fim)

    int rem = 63 - k;                        // remaining columns
    int RR = rem < REGC ? rem : REGC;        // of which, in the register window
#pragma unroll
    for (int ch = 0; ch < 6; ++ch) {
      if (ch * 8 < RR) {                     // uniform scalar guard, chunk=8
        int c0 = ch * 8 + 1;
        int Li[8];
#pragma unroll
        for (int e = 0; e < 8; ++e)          // batch: 8 readlanes (packed rows)
          Li[e] = __builtin_amdgcn_readlane(h2i(a2[c0 + e]), p);
#pragma unroll
        for (int e = 0; e < 8; ++e) {
          __half2 P = i2h(Li[e]);
          // (re',im') = (re,im) - fre*(lr,li) + fim*(li,-lr): 2 pk_fma
          // (__lowhigh2highlow folds into pk_fma op_sel -- r13 errata)
          __half2 tmp = __hfma2(nfre2, P, a2[c0 + e]);
          a2[c0 + e - 1] = __hfma2(fim2, __lowhigh2highlow(P), tmp);
        }
      }
    }

    if (k < LDSC) {
      // LDS-resident cols cl=k..17 (matrix cols 46+cl). Lanes read their own
      // row (consecutive -> 2-way alias, free); pivot row is a same-address
      // broadcast (free). Retired/pivot lanes have fre=fim=0 -> no-op update.
      int base = (b * LDSC + k) * 64;
      int own = base + r;
      int pva = base + p;
      {
        // cl = k: this col migrates into the freed reg slot; skip write-back.
        __half2 pv = i2h(sm32[pva]);
        __half2 mine = i2h(sm32[own]);
        __half2 tmp = __hfma2(nfre2, pv, mine);
        a2[REGC - 1] = __hfma2(fim2, __lowhigh2highlow(pv), tmp);
      }
#pragma unroll 4
      for (int cl = k + 1; cl < LDSC; ++cl) {
        own += 64; pva += 64;
        __half2 pv = i2h(sm32[pva]);
        __half2 mine = i2h(sm32[own]);
        __half2 tmp = __hfma2(nfre2, pv, mine);
        sm32[own] = h2i(__hfma2(fim2, __lowhigh2highlow(pv), tmp));
      }
    }
  }
  {
    float fr0 = __low2float(a2[0]);
    float fi0 = __high2float(a2[0]);
    if (active) pivmag = fmaf(fr0, fr0, fi0 * fi0);  // last surviving row
  }

  float logsum = 0.5f * __logf(pivmag);      // one log per lane; sum = logdet
#pragma unroll
  for (int off = 32; off > 0; off >>= 1) logsum += __shfl_xor(logsum, off);
  if (r == 0) atomicAdd(&logdet[b], weight * logsum);
}

// ---------------------------------------------------------------------------
extern "C" void kernel_launch(void* const* d_in, const int* in_sizes, int n_in,
                              void* d_out, int out_size, void* d_ws, size_t ws_size,
                              hipStream_t stream) {
  const float* conv_in = (const float*)d_in[0];   // [4,64,64,64]
  const float* K       = (const float*)d_in[1];   // [4,64,64,3,3]
  const float* bias    = (const float*)d_in[2];   // [4,64,1,1]
  float* out = (float*)d_out;                     // conv_out (1048576) ++ logdet (4)
  float* logdet = out + 1048576;

  hipMemsetAsync(logdet, 0, 4 * sizeof(float), stream);
  fused_kernel<<<dim3(2306), dim3(256), 0, stream>>>(conv_in, K, bias, out, logdet);
}

// Round 3
// 354.592 us; speedup vs baseline: 1.0047x; 1.0047x over previous
//
#include <hip/hip_runtime.h>
#include <hip/hip_fp16.h>
#include <math.h>

#define TAU 0.5f   // |pivot|^2 threshold (f32) for the fast pivot path

// ---------------------------------------------------------------------------
// Fused kernel: 2306 blocks x 256 threads (structure = round 12).
//   bid % 9 == 8 (bid<2304)  -> conv block  cid = bid/9        (256 blocks)
//   else                     -> logdet block, key = lid        (2050 blocks)
//
// Round-18 delta: the no-spill occupancy experiment. r17 (REGC=46) spilled:
// a2[49]+15 temps = 64 hit the launch_bounds cap exactly -> allocator
// collapsed to 32 VGPR + 50MB scratch (WRITE_SIZE 4.3->37MB), dur flat.
// But occupancy DID reach 55% and scratch latency was absorbed -> the
// latency-bound hypothesis stays open. Now: REGC=44/LDSC=20:
//   VGPR: a2[45]+15 ~ 60 <= 64 (r16 calibration: a2[41]+15 = 56 measured)
//   LDS:  4*20*64*4 = 20480 B -> 8 blocks/CU exactly -> 32 waves/CU.
// Chunk loop: 5 full 8-wide chunks (slots 1..40) + 4-wide tail (41..44),
// single pad slot a2[44]. Everything else = r16 verbatim.
// Inner reg loop = r12 (readlane broadcast, op_sel-folded swap): r8/r13/r14
// established DS-pipe broadcasts and SALU swaps both regress.
// SQ_LDS_BANK_CONFLICT (8.26M, constant r0-r2) is conv-tile 2-way aliasing
// (free per m136) -- not actionable.
// ---------------------------------------------------------------------------
#define REGC 44   // columns held in registers (sliding window)
#define LDSC 20   // columns staged in LDS (cols 44..63 at k=0)
#define PADC 45   // a2 size: slots 0..43 real, slot 44 = pad

__device__ __forceinline__ int h2i(__half2 h) { int i; __builtin_memcpy(&i, &h, 4); return i; }
__device__ __forceinline__ __half2 i2h(int i) { __half2 h; __builtin_memcpy(&h, &i, 4); return h; }

__global__ __launch_bounds__(256, 8) void fused_kernel(
    const float* __restrict__ x, const float* __restrict__ K,
    const float* __restrict__ bias, float* __restrict__ out,
    float* __restrict__ logdet) {
  // conv view:   w[576] + tile[64*65] = 4736 floats = 18944 B
  // logdet view: 4 waves x 20 cols x 64 rows of half2-as-int = 5120 ints
  __shared__ float smem[5120];               // 20480 B -> 8 blocks/CU exactly
  int bid = blockIdx.x;
  int t = threadIdx.x;

  bool isConv = false;
  int cid = 0, lid = 0;
  if (bid < 2304) {
    int q9 = bid / 9, m9 = bid - q9 * 9;
    if (m9 == 8) { isConv = true; cid = q9; }
    else lid = bid - (bid + 1) / 9;          // 0..2047
  } else {
    lid = bid - 256;                         // 2048, 2049
  }

  if (isConv) {
    // ================= conv =================
    int b = cid >> 6, co = cid & 63;
    float* w = smem;                         // 576
    float* tile = smem + 576;                // 64*65

    for (int i = t; i < 576; i += 256) {
      float vv = K[(size_t)((b * 64 + co) * 64) * 9 + i];
      if (i == co * 9 + 4) vv += 1.0f;       // identity: ci==co, center tap
      w[i] = vv;
    }

    int ty = t >> 2;
    int tx = t & 3;
    int x0 = tx << 4;
    float bval = bias[b * 64 + co];
    float acc[16];
#pragma unroll
    for (int i = 0; i < 16; ++i) acc[i] = bval;

    const float* xb = x + (size_t)(b * 64) * 4096;
    for (int ci = 0; ci < 64; ++ci) {
      __syncthreads();                       // WAR on tile (and w on first iter)
      const float* xc = xb + (size_t)ci * 4096;
#pragma unroll
      for (int j = 0; j < 16; ++j) {
        int i = t + 256 * j;
        tile[(i >> 6) * 65 + (i & 63)] = xc[i];
      }
      __syncthreads();

      int ym = ((ty - 1) & 63) * 65;
      int yc = ty * 65;
      int yp = ((ty + 1) & 63) * 65;

      // one 18-wide row buffer per kernel-row: peak ~50 VGPR (fits 64 cap)
      {
        float wa = w[ci * 9 + 0], wb = w[ci * 9 + 1], wcc = w[ci * 9 + 2];
        float in[18];
#pragma unroll
        for (int ix = 0; ix < 18; ++ix) in[ix] = tile[ym + ((x0 + ix - 1) & 63)];
#pragma unroll
        for (int px = 0; px < 16; ++px)
          acc[px] = fmaf(wa, in[px], fmaf(wb, in[px + 1], fmaf(wcc, in[px + 2], acc[px])));
      }
      {
        float wa = w[ci * 9 + 3], wb = w[ci * 9 + 4], wcc = w[ci * 9 + 5];
        float in[18];
#pragma unroll
        for (int ix = 0; ix < 18; ++ix) in[ix] = tile[yc + ((x0 + ix - 1) & 63)];
#pragma unroll
        for (int px = 0; px < 16; ++px)
          acc[px] = fmaf(wa, in[px], fmaf(wb, in[px + 1], fmaf(wcc, in[px + 2], acc[px])));
      }
      {
        float wa = w[ci * 9 + 6], wb = w[ci * 9 + 7], wcc = w[ci * 9 + 8];
        float in[18];
#pragma unroll
        for (int ix = 0; ix < 18; ++ix) in[ix] = tile[yp + ((x0 + ix - 1) & 63)];
#pragma unroll
        for (int px = 0; px < 16; ++px)
          acc[px] = fmaf(wa, in[px], fmaf(wb, in[px + 1], fmaf(wcc, in[px + 2], acc[px])));
      }
    }

    float* op = out + (size_t)(b * 64 + co) * 4096 + ty * 64 + x0;
#pragma unroll
    for (int i = 0; i < 16; i += 4) {
      *(float4*)(op + i) = make_float4(acc[i], acc[i + 1], acc[i + 2], acc[i + 3]);
    }
    return;
  }

  // ================= logdet =================
  int* sm32 = (int*)smem;                    // [4 waves][20 cols][64 rows]
  int u, v;
  if (lid < 33) { u = 0; v = lid; }
  else if (lid < 2017) { int q = lid - 33; u = 1 + (q >> 6); v = q & 63; }
  else { u = 32; v = lid - 2017; }
  float weight = (((u & 31) == 0) && ((v & 31) == 0)) ? 1.0f : 2.0f;

  int b = t >> 6;                            // wave id == batch
  int r = t & 63;                            // lane == matrix row

  // twiddles w[kh*3+kw] = e^{-2*pi*i*(u*kh+v*kw)/64}; block-uniform -> SGPRs
  int swr[9], swi[9];
  {
    float Ar[3], Ai[3], Br[3], Bi[3];
    const float k2pi = -6.283185307179586f / 64.0f;
    float su, cu, sv, cv;
    __sincosf(k2pi * (float)u, &su, &cu);
    __sincosf(k2pi * (float)v, &sv, &cv);
    Ar[0] = 1.0f; Ai[0] = 0.0f; Ar[1] = cu; Ai[1] = su;
    Ar[2] = cu * cu - su * su; Ai[2] = 2.0f * cu * su;
    Br[0] = 1.0f; Bi[0] = 0.0f; Br[1] = cv; Bi[1] = sv;
    Br[2] = cv * cv - sv * sv; Bi[2] = 2.0f * cv * sv;
#pragma unroll
    for (int kh = 0; kh < 3; ++kh)
#pragma unroll
      for (int kw = 0; kw < 3; ++kw) {
        float wrv = Ar[kh] * Br[kw] - Ai[kh] * Bi[kw];
        float wiv = Ar[kh] * Bi[kw] + Ai[kh] * Br[kw];
        swr[kh * 3 + kw] = __builtin_amdgcn_readfirstlane(__float_as_int(wrv));
        swi[kh * 3 + kw] = __builtin_amdgcn_readfirstlane(__float_as_int(wiv));
      }
  }

  // Build row r of Khat: cols 0..REGC-1 -> registers, REGC..63 -> LDS.
  // Scalar loads keep build-phase VGPR peak under the 64 cap (K rows are
  // L1/L2 resident; r16/r17 showed the extra VMEM issues are absorbed).
  __half2 a2[PADC];
  const float* Kp = K + (size_t)(b * 64 + r) * 576;
#pragma unroll
  for (int c = 0; c < 64; ++c) {
    float re = 0.0f, im = 0.0f;
#pragma unroll
    for (int t9 = 0; t9 < 9; ++t9) {
      float kv = Kp[c * 9 + t9];
      re = fmaf(kv, __int_as_float(swr[t9]), re);
      im = fmaf(kv, __int_as_float(swi[t9]), im);
    }
    if (c == r) { re += __int_as_float(swr[4]); im += __int_as_float(swi[4]); }
    __half2 h = __floats2half2_rn(re, im);
    if (c < REGC) a2[c] = h;
    else sm32[(b * LDSC + (c - REGC)) * 64 + r] = h2i(h);
  }
  a2[REGC] = __floats2half2_rn(0.0f, 0.0f);  // single pad slot (slot 44)

  bool active = true;
  float pivmag = 1.0f;                       // each lane's own pivot |.|^2 (f32)

  for (int k = 0; k < 63; ++k) {
    float fr0 = __low2float(a2[0]);
    float fi0 = __high2float(a2[0]);
    float mag = fmaf(fr0, fr0, fi0 * fi0);
    bool cand = active && (mag >= TAU);
    unsigned long long candm = __ballot(cand);
    int p;
    if (candm != 0ULL) {
      p = __ffsll(candm) - 1;                // fast path: first big-enough pivot
    } else {                                 // rare: all remaining pivots tiny
      float mm = active ? mag : -1.0f;
#pragma unroll
      for (int off = 32; off > 0; off >>= 1) mm = fmaxf(mm, __shfl_xor(mm, off));
      unsigned long long mx = __ballot(active && (mag == mm));
      if (mx == 0ULL) mx = __ballot(active); // degenerate (NaN) guard
      p = __ffsll(mx) - 1;
    }
    p &= 63;                                 // uniform (ballot-derived), valid lane

    bool isPiv = (r == p);
    pivmag = isPiv ? mag : pivmag;           // latch; log deferred to the end
    active = active && !isPiv;

    __half2 pivh = i2h(__builtin_amdgcn_readlane(h2i(a2[0]), p));
    float pr = __low2float(pivh);
    float pi = __high2float(pivh);
    float inv = __builtin_amdgcn_rcpf(fmaf(pr, pr, pi * pi));
    float fre = (fr0 * pr + fi0 * pi) * inv;
    float fim = (fi0 * pr - fr0 * pi) * inv;
    fre = active ? fre : 0.0f;               // pivot + retired lanes: shift-only
    fim = active ? fim : 0.0f;
    __half2 nfre2 = __float2half2_rn(-fre);                     // (-fre, -fre)
    __half2 fim2 = __halves2half2(__float2half_rn(fim),
                                  __float2half_rn(-fim));       // (fim, -fim)

    int rem = 63 - k;                        // remaining columns
    int RR = rem < REGC ? rem : REGC;        // of which, in the register window
#pragma unroll
    for (int ch = 0; ch < 5; ++ch) {
      if (ch * 8 < RR) {                     // uniform scalar guard, chunk=8
        int c0 = ch * 8 + 1;
        int Li[8];
#pragma unroll
        for (int e = 0; e < 8; ++e)          // batch: 8 readlanes (packed rows)
          Li[e] = __builtin_amdgcn_readlane(h2i(a2[c0 + e]), p);
#pragma unroll
        for (int e = 0; e < 8; ++e) {
          __half2 P = i2h(Li[e]);
          // (re',im') = (re,im) - fre*(lr,li) + fim*(li,-lr): 2 pk_fma
          // (__lowhigh2highlow folds into pk_fma op_sel -- r13 errata)
          __half2 tmp = __hfma2(nfre2, P, a2[c0 + e]);
          a2[c0 + e - 1] = __hfma2(fim2, __lowhigh2highlow(P), tmp);
        }
      }
    }
    if (40 < RR) {                           // 4-wide tail: slots 41..44
      int Li[4];
#pragma unroll
      for (int e = 0; e < 4; ++e)
        Li[e] = __builtin_amdgcn_readlane(h2i(a2[41 + e]), p);
#pragma unroll
      for (int e = 0; e < 4; ++e) {
        __half2 P = i2h(Li[e]);
        __half2 tmp = __hfma2(nfre2, P, a2[41 + e]);
        a2[40 + e] = __hfma2(fim2, __lowhigh2highlow(P), tmp);
      }
    }

    if (k < LDSC) {
      // LDS-resident cols cl=k..19 (matrix cols 44+cl). Lanes read their own
      // row (consecutive -> 2-way alias, free); pivot row is a same-address
      // broadcast (free). Retired/pivot lanes have fre=fim=0 -> no-op update.
      int base = (b * LDSC + k) * 64;
      int own = base + r;
      int pva = base + p;
      {
        // cl = k: this col migrates into the freed reg slot; skip write-back.
        __half2 pv = i2h(sm32[pva]);
        __half2 mine = i2h(sm32[own]);
        __half2 tmp = __hfma2(nfre2, pv, mine);
        a2[REGC - 1] = __hfma2(fim2, __lowhigh2highlow(pv), tmp);
      }
#pragma unroll 4
      for (int cl = k + 1; cl < LDSC; ++cl) {
        own += 64; pva += 64;
        __half2 pv = i2h(sm32[pva]);
        __half2 mine = i2h(sm32[own]);
        __half2 tmp = __hfma2(nfre2, pv, mine);
        sm32[own] = h2i(__hfma2(fim2, __lowhigh2highlow(pv), tmp));
      }
    }
  }
  {
    float fr0 = __low2float(a2[0]);
    float fi0 = __high2float(a2[0]);
    if (active) pivmag = fmaf(fr0, fr0, fi0 * fi0);  // last surviving row
  }

  float logsum = 0.5f * __logf(pivmag);      // one log per lane; sum = logdet
#pragma unroll
  for (int off = 32; off > 0; off >>= 1) logsum += __shfl_xor(logsum, off);
  if (r == 0) atomicAdd(&logdet[b], weight * logsum);
}

// ---------------------------------------------------------------------------
extern "C" void kernel_launch(void* const* d_in, const int* in_sizes, int n_in,
                              void* d_out, int out_size, void* d_ws, size_t ws_size,
                              hipStream_t stream) {
  const float* conv_in = (const float*)d_in[0];   // [4,64,64,64]
  const float* K       = (const float*)d_in[1];   // [4,64,64,3,3]
  const float* bias    = (const float*)d_in[2];   // [4,64,1,1]
  float* out = (float*)d_out;                     // conv_out (1048576) ++ logdet (4)
  float* logdet = out + 1048576;

  hipMemsetAsync(logdet, 0, 4 * sizeof(float), stream);
  fused_kernel<<<dim3(2306), dim3(256), 0, stream>>>(conv_in, K, bias, out, logdet);
}

// Round 5
// 326.401 us; speedup vs baseline: 1.0915x; 1.0864x over previous
//
#include <hip/hip_runtime.h>
#include <hip/hip_fp16.h>
#include <math.h>

#define TAU 0.5f   // |pivot|^2 threshold (f32) for the fast pivot path

// ---------------------------------------------------------------------------
// Fused kernel: 2306 blocks x 256 threads.
//   bid < 256   -> conv block,   cid = bid        (CONV FIRST -- r19 delta)
//   bid >= 256  -> logdet block, lid = bid - 256  (0..2049)
//
// [r20 = r19 resubmitted verbatim: round-4 bench died with "MI355X container
//  failed twice" (infra acquisition failure, no kernel verdict). Source
//  audited: uniform barriers, no OOB (smem = 576+64*68 = 4928 exactly),
//  logdet path byte-identical to the passing r12/r0 kernel.]
//
// Round-19 post-mortem of r16-r18: LDS-staging/occupancy arc is a dead end.
//   - dur pinned ~303-321us across occupancy 26->56%, spill or no spill.
//   - r0/r12 (76 VGPR, pure-register a2[65]) had the FASTEST dispatches.
//   - r0's time-averaged occupancy 26% << static cap 75% => drain/tail:
//     long conv blocks (~50us, DS-issue-heavy) scattered at bid%9==8 start
//     late and straggle. Fix the tail, not the residency cap.
// r19 deltas (conv-only; logdet = r12 verbatim):
//   1. conv blocks at bid 0..255: all start at t=0, 1/CU, overlap logdet.
//   2. tile stride 65->68 (16B-aligned rows; 2-way alias, free per m136).
//      Staging: 4x dwordx4 + 4x ds_write_b128 (was 16+16 scalar).
//      Row reads: 12x ds_read_b128 + 6 scalar edges (was 54 scalar).
//      Per-thread-per-ci issues: 86 -> 26.
// Logdet inner loop = r12 verbatim (readlane broadcast, op_sel-folded swap):
// r8/r13/r14 established DS broadcasts and SALU swaps regress; r16-r18
// established LDS column staging regresses or spills.
// ---------------------------------------------------------------------------
__device__ __forceinline__ int h2i(__half2 h) { int i; __builtin_memcpy(&i, &h, 4); return i; }
__device__ __forceinline__ __half2 i2h(int i) { __half2 h; __builtin_memcpy(&h, &i, 4); return h; }

__global__ __launch_bounds__(256, 3) void fused_kernel(
    const float* __restrict__ x, const float* __restrict__ K,
    const float* __restrict__ bias, float* __restrict__ out,
    float* __restrict__ logdet) {
  __shared__ float smem[4928];               // conv: w[576] + tile[64*68]
  int bid = blockIdx.x;
  int t = threadIdx.x;

  if (bid < 256) {
    // ================= conv =================
    int b = bid >> 6, co = bid & 63;
    float* w = smem;                         // 576
    float* tile = smem + 576;                // 64*68 (stride 68: 16B-aligned)

    for (int i = t; i < 576; i += 256) {
      float vv = K[(size_t)((b * 64 + co) * 64) * 9 + i];
      if (i == co * 9 + 4) vv += 1.0f;       // identity: ci==co, center tap
      w[i] = vv;
    }

    int ty = t >> 2;
    int tx = t & 3;
    int x0 = tx << 4;
    float bval = bias[b * 64 + co];
    float acc[16];
#pragma unroll
    for (int i = 0; i < 16; ++i) acc[i] = bval;

    const float* xb = x + (size_t)(b * 64) * 4096;
    for (int ci = 0; ci < 64; ++ci) {
      __syncthreads();                       // WAR on tile (and w on first iter)
      const float4* xc4 = (const float4*)(xb + (size_t)ci * 4096);
#pragma unroll
      for (int j = 0; j < 4; ++j) {          // 4x (dwordx4 load + b128 LDS write)
        int i4 = t + 256 * j;                // float4 index 0..1023
        int row = i4 >> 4;                   // 16 float4 per 64-wide row
        int col = (i4 & 15) << 2;
        float4 vv = xc4[i4];
        *(float4*)&tile[row * 68 + col] = vv;
      }
      __syncthreads();

      float w0 = w[ci * 9 + 0], w1 = w[ci * 9 + 1], w2 = w[ci * 9 + 2];
      float w3 = w[ci * 9 + 3], w4 = w[ci * 9 + 4], w5 = w[ci * 9 + 5];
      float w6 = w[ci * 9 + 6], w7 = w[ci * 9 + 7], w8 = w[ci * 9 + 8];

      int ym = ((ty - 1) & 63) * 68;
      int yc = ty * 68;
      int yp = ((ty + 1) & 63) * 68;
      float in0[18], in1[18], in2[18];
#pragma unroll
      for (int q = 0; q < 4; ++q) {          // interior: 12x ds_read_b128
        float4 v0 = *(const float4*)&tile[ym + x0 + 4 * q];
        float4 v1 = *(const float4*)&tile[yc + x0 + 4 * q];
        float4 v2 = *(const float4*)&tile[yp + x0 + 4 * q];
        in0[1 + 4 * q] = v0.x; in0[2 + 4 * q] = v0.y; in0[3 + 4 * q] = v0.z; in0[4 + 4 * q] = v0.w;
        in1[1 + 4 * q] = v1.x; in1[2 + 4 * q] = v1.y; in1[3 + 4 * q] = v1.z; in1[4 + 4 * q] = v1.w;
        in2[1 + 4 * q] = v2.x; in2[2 + 4 * q] = v2.y; in2[3 + 4 * q] = v2.z; in2[4 + 4 * q] = v2.w;
      }
      in0[0]  = tile[ym + ((x0 - 1) & 63)];  // 6 scalar edge reads (wrap)
      in0[17] = tile[ym + ((x0 + 16) & 63)];
      in1[0]  = tile[yc + ((x0 - 1) & 63)];
      in1[17] = tile[yc + ((x0 + 16) & 63)];
      in2[0]  = tile[yp + ((x0 - 1) & 63)];
      in2[17] = tile[yp + ((x0 + 16) & 63)];
#pragma unroll
      for (int px = 0; px < 16; ++px) {
        float a = acc[px];
        a = fmaf(w0, in0[px], a); a = fmaf(w1, in0[px + 1], a); a = fmaf(w2, in0[px + 2], a);
        a = fmaf(w3, in1[px], a); a = fmaf(w4, in1[px + 1], a); a = fmaf(w5, in1[px + 2], a);
        a = fmaf(w6, in2[px], a); a = fmaf(w7, in2[px + 1], a); a = fmaf(w8, in2[px + 2], a);
        acc[px] = a;
      }
    }

    float* op = out + (size_t)(b * 64 + co) * 4096 + ty * 64 + x0;
#pragma unroll
    for (int i = 0; i < 16; i += 4) {
      *(float4*)(op + i) = make_float4(acc[i], acc[i + 1], acc[i + 2], acc[i + 3]);
    }
    return;
  }

  // ================= logdet =================
  int lid = bid - 256;                       // 0..2049
  int u, v;
  if (lid < 33) { u = 0; v = lid; }
  else if (lid < 2017) { int q = lid - 33; u = 1 + (q >> 6); v = q & 63; }
  else { u = 32; v = lid - 2017; }
  float weight = (((u & 31) == 0) && ((v & 31) == 0)) ? 1.0f : 2.0f;

  int b = t >> 6;                            // wave id == batch
  int r = t & 63;                            // lane == matrix row

  // twiddles w[kh*3+kw] = e^{-2*pi*i*(u*kh+v*kw)/64} via complex power products
  float Ar[3], Ai[3], Br[3], Bi[3];
  {
    const float k2pi = -6.283185307179586f / 64.0f;
    float su, cu, sv, cv;
    __sincosf(k2pi * (float)u, &su, &cu);
    __sincosf(k2pi * (float)v, &sv, &cv);
    Ar[0] = 1.0f; Ai[0] = 0.0f; Ar[1] = cu; Ai[1] = su;
    Ar[2] = cu * cu - su * su; Ai[2] = 2.0f * cu * su;
    Br[0] = 1.0f; Bi[0] = 0.0f; Br[1] = cv; Bi[1] = sv;
    Br[2] = cv * cv - sv * sv; Bi[2] = 2.0f * cv * sv;
  }
  float wr[9], wi[9];
#pragma unroll
  for (int kh = 0; kh < 3; ++kh)
#pragma unroll
    for (int kw = 0; kw < 3; ++kw) {
      wr[kh * 3 + kw] = Ar[kh] * Br[kw] - Ai[kh] * Bi[kw];
      wi[kh * 3 + kw] = Ar[kh] * Bi[kw] + Ai[kh] * Br[kw];
    }

  // Build row r of Khat in fp32, pack each column to f16x2 immediately.
  __half2 a2[65];
  const float4* Kp4 = (const float4*)(K + (size_t)(b * 64 + r) * 576);
#pragma unroll
  for (int g = 0; g < 16; ++g) {             // 16 groups x 4 columns
    float f[36];
#pragma unroll
    for (int qq = 0; qq < 9; ++qq) {
      float4 vv = Kp4[g * 9 + qq];
      f[qq * 4 + 0] = vv.x; f[qq * 4 + 1] = vv.y; f[qq * 4 + 2] = vv.z; f[qq * 4 + 3] = vv.w;
    }
#pragma unroll
    for (int cc = 0; cc < 4; ++cc) {
      int c = g * 4 + cc;
      float re = 0.0f, im = 0.0f;
#pragma unroll
      for (int t9 = 0; t9 < 9; ++t9) {
        float kv = f[cc * 9 + t9];
        re = fmaf(kv, wr[t9], re);
        im = fmaf(kv, wi[t9], im);
      }
      if (c == r) { re += wr[4]; im += wi[4]; }  // identity: center-tap delta
      a2[c] = __floats2half2_rn(re, im);
    }
  }
  a2[64] = __floats2half2_rn(0.0f, 0.0f);    // pad slot for chunk overshoot

  bool active = true;
  float pivmag = 1.0f;                       // each lane's own pivot |.|^2 (f32)

  for (int k = 0; k < 63; ++k) {
    float fr0 = __low2float(a2[0]);
    float fi0 = __high2float(a2[0]);
    float mag = fmaf(fr0, fr0, fi0 * fi0);
    bool cand = active && (mag >= TAU);
    unsigned long long candm = __ballot(cand);
    int p;
    if (candm != 0ULL) {
      p = __ffsll(candm) - 1;                // fast path: first big-enough pivot
    } else {                                 // rare: all remaining pivots tiny
      float mm = active ? mag : -1.0f;
#pragma unroll
      for (int off = 32; off > 0; off >>= 1) mm = fmaxf(mm, __shfl_xor(mm, off));
      unsigned long long mx = __ballot(active && (mag == mm));
      if (mx == 0ULL) mx = __ballot(active); // degenerate (NaN) guard
      p = __ffsll(mx) - 1;
    }
    p &= 63;                                 // uniform (ballot-derived), valid lane

    bool isPiv = (r == p);
    pivmag = isPiv ? mag : pivmag;           // latch; log deferred to the end
    active = active && !isPiv;

    __half2 pivh = i2h(__builtin_amdgcn_readlane(h2i(a2[0]), p));
    float pr = __low2float(pivh);
    float pi = __high2float(pivh);
    float inv = __builtin_amdgcn_rcpf(fmaf(pr, pr, pi * pi));
    float fre = (fr0 * pr + fi0 * pi) * inv;
    float fim = (fi0 * pr - fr0 * pi) * inv;
    fre = active ? fre : 0.0f;               // pivot + retired lanes: shift-only
    fim = active ? fim : 0.0f;
    __half2 nfre2 = __float2half2_rn(-fre);                     // (-fre, -fre)
    __half2 fim2 = __halves2half2(__float2half_rn(fim),
                                  __float2half_rn(-fim));       // (fim, -fim)

    int rem = 63 - k;                        // remaining columns at slots 1..rem
#pragma unroll
    for (int ch = 0; ch < 8; ++ch) {
      if (ch * 8 < rem) {                    // uniform scalar guard, chunk=8
        int c0 = ch * 8 + 1;
        int Li[8];
#pragma unroll
        for (int e = 0; e < 8; ++e)          // batch: 8 readlanes (packed rows)
          Li[e] = __builtin_amdgcn_readlane(h2i(a2[c0 + e]), p);
#pragma unroll
        for (int e = 0; e < 8; ++e) {
          __half2 P = i2h(Li[e]);
          // (re',im') = (re,im) - fre*(lr,li) + fim*(li,-lr): 2 pk_fma
          // (__lowhigh2highlow folds into pk_fma op_sel -- r13 errata)
          __half2 tmp = __hfma2(nfre2, P, a2[c0 + e]);
          a2[c0 + e - 1] = __hfma2(fim2, __lowhigh2highlow(P), tmp);
        }
      }
    }
  }
  {
    float fr0 = __low2float(a2[0]);
    float fi0 = __high2float(a2[0]);
    if (active) pivmag = fmaf(fr0, fr0, fi0 * fi0);  // last surviving row
  }

  float logsum = 0.5f * __logf(pivmag);      // one log per lane; sum = logdet
#pragma unroll
  for (int off = 32; off > 0; off >>= 1) logsum += __shfl_xor(logsum, off);
  if (r == 0) atomicAdd(&logdet[b], weight * logsum);
}

// ---------------------------------------------------------------------------
extern "C" void kernel_launch(void* const* d_in, const int* in_sizes, int n_in,
                              void* d_out, int out_size, void* d_ws, size_t ws_size,
                              hipStream_t stream) {
  const float* conv_in = (const float*)d_in[0];   // [4,64,64,64]
  const float* K       = (const float*)d_in[1];   // [4,64,64,3,3]
  const float* bias    = (const float*)d_in[2];   // [4,64,1,1]
  float* out = (float*)d_out;                     // conv_out (1048576) ++ logdet (4)
  float* logdet = out + 1048576;

  hipMemsetAsync(logdet, 0, 4 * sizeof(float), stream);
  fused_kernel<<<dim3(2306), dim3(256), 0, stream>>>(conv_in, K, bias, out, logdet);
}